// Round 16
// baseline (209.926 us; speedup 1.0000x reference)
//
#include <hip/hip_runtime.h>

#define NR 4000
#define TS 60
#define DF 6
#define HD 64
#define MB 16    // rows per GRU block
#define ARB 32   // rows per attn block

typedef __attribute__((ext_vector_type(8))) short bf8_t;
typedef __attribute__((ext_vector_type(4))) short bf4_t;
typedef __attribute__((ext_vector_type(4))) float f32x4;

__device__ __forceinline__ float sigf(float x) { return 1.0f / (1.0f + __expf(-x)); }
__device__ __forceinline__ float tanhfast(float x) { return 1.0f - 2.0f / (1.0f + __expf(2.0f * x)); }

__device__ __forceinline__ unsigned short f2bf(float v) {  // RTN (weights, one-time)
  union { float f; unsigned u; } x; x.f = v;
  unsigned r = (x.u + 0x7fffu + ((x.u >> 16) & 1u)) >> 16;
  return (unsigned short)r;
}
__device__ __forceinline__ float bf2f(unsigned short h) {
  union { unsigned u; float f; } y; y.u = ((unsigned)h) << 16; return y.f;
}
__device__ __forceinline__ void split8(const float* v, bf8_t& hi, bf8_t& lo) {
#pragma unroll
  for (int j = 0; j < 8; ++j) {
    unsigned short h = f2bf(v[j]);
    float rem = v[j] - bf2f(h);
    hi[j] = (short)h;
    lo[j] = (short)f2bf(rem);
  }
}

// ---------------------------------------------------------------------------
// Kernel 0: rel (4000x4000x3 f32, ~half L3-resident across replays) -> uint8
// msum (16MB, exact: values in {0..3}). Standalone: rounds 14/15 proved that
// co-residency with the GRU costs the GRU 60% more time than msum saves.
// ---------------------------------------------------------------------------
__global__ __launch_bounds__(256) void msum_kernel(
    const float* __restrict__ rel, unsigned char* __restrict__ msum8) {
  const size_t ngroups = (size_t)NR * NR / 4;  // groups of 4 (i,j) pairs
  const size_t stride = (size_t)gridDim.x * 256;
  for (size_t g = (size_t)blockIdx.x * 256 + threadIdx.x; g < ngroups; g += stride) {
    const float4* rp = (const float4*)(rel + 12 * g);
    float4 v0 = rp[0], v1 = rp[1], v2 = rp[2];
    uchar4 o;
    o.x = (unsigned char)(v0.x + v0.y + v0.z);
    o.y = (unsigned char)(v0.w + v1.x + v1.y);
    o.z = (unsigned char)(v1.z + v1.w + v2.x);
    o.w = (unsigned char)(v2.y + v2.z + v2.w);
    *(uchar4*)&msum8[4 * g] = o;
  }
}

// ---------------------------------------------------------------------------
// Kernel 1: fused 2-layer GRU via split-bf16 MFMA — round-9/11 proven version
// (121us): 250 blocks x 256 threads, 4 waves (wave owns 16 units), weights
// resident as 144 hi/lo bf16 frags (AGPR), skewed single-barrier phases,
// producer-side hi/lo h split, consumer raw ds_read frags.
// Failed alternatives (keep for the record): (256,2) spills (r6); 8-wave
// lo-in-LDS dup-rows (r10); fused msum co-residency (r14); setprio (r15).
// ---------------------------------------------------------------------------
__global__ __launch_bounds__(256, 1) void gru_mfma(
    const float* __restrict__ x,
    const float* __restrict__ Wih0, const float* __restrict__ Whh0,
    const float* __restrict__ bih0, const float* __restrict__ bhh0,
    const float* __restrict__ Wih1, const float* __restrict__ Whh1,
    const float* __restrict__ bih1, const float* __restrict__ bhh1,
    const float* __restrict__ Wac,
    float* __restrict__ xh_out, float* __restrict__ a_out, float* __restrict__ c_out) {
  __shared__ float xldsT[TS][MB][12];
  __shared__ __align__(16) unsigned short h0hiL[2][16][76];
  __shared__ __align__(16) unsigned short h0loL[2][16][76];
  __shared__ __align__(16) unsigned short h1hiL[2][16][76];
  __shared__ __align__(16) unsigned short h1loL[2][16][76];
  __shared__ float red[2][4][MB];

  const int tid = threadIdx.x;
  const int w = tid >> 6;
  const int lane = tid & 63;
  const int lg = lane >> 4;
  const int lm = lane & 15;
  const int unit = w * 16 + lm;
  const int r0 = blockIdx.x * MB;

  for (int idx = tid; idx < MB * 360; idx += 256) {
    int rr = idx / 360, cc = idx - rr * 360;
    int f = cc / 60, t = cc - f * 60;
    xldsT[t][rr][f] = x[(size_t)r0 * 360 + idx];
  }

  bf8_t wB[3][3][2][2];
  {
    const float* mats[3] = {Whh0, Wih1, Whh1};
#pragma unroll
    for (int m = 0; m < 3; ++m)
#pragma unroll
      for (int g = 0; g < 3; ++g)
#pragma unroll
        for (int kt = 0; kt < 2; ++kt) {
          const float* src = mats[m] + (size_t)(g * 64 + unit) * 64 + kt * 32 + 8 * lg;
          float v[8];
          *(float4*)&v[0] = *(const float4*)&src[0];
          *(float4*)&v[4] = *(const float4*)&src[4];
          split8(v, wB[m][g][kt][0], wB[m][g][kt][1]);
        }
  }
  float wih0g[3][DF];
#pragma unroll
  for (int g = 0; g < 3; ++g)
#pragma unroll
    for (int f = 0; f < DF; ++f)
      wih0g[g][f] = Wih0[(size_t)(g * 64 + unit) * DF + f];

  const float bi0r = bih0[unit], bi0z = bih0[64 + unit], bi0n = bih0[128 + unit];
  const float bh0r = bhh0[unit], bh0z = bhh0[64 + unit], bh0n = bhh0[128 + unit];
  const float c1R = bih1[unit] + bhh1[unit];
  const float c1Z = bih1[64 + unit] + bhh1[64 + unit];
  const float b1xn = bih1[128 + unit], b1hn = bhh1[128 + unit];

  bf8_t a0[2][2], a1[2][2];
  bf8_t zf = {};
#pragma unroll
  for (int kt = 0; kt < 2; ++kt)
#pragma unroll
    for (int h = 0; h < 2; ++h) { a0[kt][h] = zf; a1[kt][h] = zf; }
  float h0c[4] = {0.f, 0.f, 0.f, 0.f};
  float h1c[4] = {0.f, 0.f, 0.f, 0.f};

  __syncthreads();

#define MF(acc, A, B) acc = __builtin_amdgcn_mfma_f32_16x16x32_bf16(A, B, acc, 0, 0, 0)
#define MF3(acc, Af, Bf) do { \
    MF(acc, Af[0], Bf[0]); MF(acc, Af[0], Bf[1]); MF(acc, Af[1], Bf[0]); } while (0)

  for (int p = 0; p <= TS; ++p) {
    const bool doL0 = (p < TS);
    const bool doL1 = (p >= 1);
    const int par = p & 1;
    f32x4 aR, aZ, aN;
    float xn0[4];
    if (doL0) {
#pragma unroll
      for (int i = 0; i < 4; ++i) {
        const int row = 4 * lg + i;
        const float* xb = &xldsT[p][row][0];
        float4 x4 = *(const float4*)xb;
        float2 x2 = *(const float2*)(xb + 4);
        float sr = bi0r, sz = bi0z, sn = bi0n;
        sr = fmaf(wih0g[0][0], x4.x, sr); sz = fmaf(wih0g[1][0], x4.x, sz); sn = fmaf(wih0g[2][0], x4.x, sn);
        sr = fmaf(wih0g[0][1], x4.y, sr); sz = fmaf(wih0g[1][1], x4.y, sz); sn = fmaf(wih0g[2][1], x4.y, sn);
        sr = fmaf(wih0g[0][2], x4.z, sr); sz = fmaf(wih0g[1][2], x4.z, sz); sn = fmaf(wih0g[2][2], x4.z, sn);
        sr = fmaf(wih0g[0][3], x4.w, sr); sz = fmaf(wih0g[1][3], x4.w, sz); sn = fmaf(wih0g[2][3], x4.w, sn);
        sr = fmaf(wih0g[0][4], x2.x, sr); sz = fmaf(wih0g[1][4], x2.x, sz); sn = fmaf(wih0g[2][4], x2.x, sn);
        sr = fmaf(wih0g[0][5], x2.y, sr); sz = fmaf(wih0g[1][5], x2.y, sz); sn = fmaf(wih0g[2][5], x2.y, sn);
        aR[i] = sr + bh0r;
        aZ[i] = sz + bh0z;
        aN[i] = bh0n;
        xn0[i] = sn;
      }
#pragma unroll
      for (int kt = 0; kt < 2; ++kt) {
        MF3(aR, a0[kt], wB[0][0][kt]);
        MF3(aZ, a0[kt], wB[0][1][kt]);
        MF3(aN, a0[kt], wB[0][2][kt]);
      }
    }
    f32x4 R1, Z1, XN, HN;
    if (doL1) {
#pragma unroll
      for (int i = 0; i < 4; ++i) { R1[i] = c1R; Z1[i] = c1Z; XN[i] = b1xn; HN[i] = b1hn; }
#pragma unroll
      for (int kt = 0; kt < 2; ++kt) {
        MF3(R1, a0[kt], wB[1][0][kt]);
        MF3(Z1, a0[kt], wB[1][1][kt]);
        MF3(XN, a0[kt], wB[1][2][kt]);
        MF3(R1, a1[kt], wB[2][0][kt]);
        MF3(Z1, a1[kt], wB[2][1][kt]);
        MF3(HN, a1[kt], wB[2][2][kt]);
      }
    }
    if (doL0) {
#pragma unroll
      for (int i = 0; i < 4; ++i) {
        float r = sigf(aR[i]);
        float z = sigf(aZ[i]);
        float n = tanhfast(xn0[i] + r * aN[i]);
        h0c[i] = n + z * (h0c[i] - n);
        const int row = 4 * lg + i;
        unsigned u = __float_as_uint(h0c[i]);
        h0hiL[par][row][unit] = (unsigned short)(u >> 16);
        float lo = h0c[i] - __uint_as_float(u & 0xffff0000u);
        h0loL[par][row][unit] = (unsigned short)(__float_as_uint(lo) >> 16);
      }
    }
    if (doL1) {
#pragma unroll
      for (int i = 0; i < 4; ++i) {
        float r = sigf(R1[i]);
        float z = sigf(Z1[i]);
        float n = tanhfast(XN[i] + r * HN[i]);
        h1c[i] = n + z * (h1c[i] - n);
      }
      if (p < TS) {
#pragma unroll
        for (int i = 0; i < 4; ++i) {
          const int row = 4 * lg + i;
          unsigned u = __float_as_uint(h1c[i]);
          h1hiL[par][row][unit] = (unsigned short)(u >> 16);
          float lo = h1c[i] - __uint_as_float(u & 0xffff0000u);
          h1loL[par][row][unit] = (unsigned short)(__float_as_uint(lo) >> 16);
        }
      }
    }
    __syncthreads();
    if (p < TS) {
#pragma unroll
      for (int kt = 0; kt < 2; ++kt) {
        const int cb = kt * 32 + 8 * lg;
        bf4_t u0 = *(const bf4_t*)&h0hiL[par][lm][cb];
        bf4_t u1 = *(const bf4_t*)&h0hiL[par][lm][cb + 4];
        a0[kt][0] = __builtin_shufflevector(u0, u1, 0, 1, 2, 3, 4, 5, 6, 7);
        bf4_t l0 = *(const bf4_t*)&h0loL[par][lm][cb];
        bf4_t l1 = *(const bf4_t*)&h0loL[par][lm][cb + 4];
        a0[kt][1] = __builtin_shufflevector(l0, l1, 0, 1, 2, 3, 4, 5, 6, 7);
      }
      if (p >= 1) {
#pragma unroll
        for (int kt = 0; kt < 2; ++kt) {
          const int cb = kt * 32 + 8 * lg;
          bf4_t u0 = *(const bf4_t*)&h1hiL[par][lm][cb];
          bf4_t u1 = *(const bf4_t*)&h1hiL[par][lm][cb + 4];
          a1[kt][0] = __builtin_shufflevector(u0, u1, 0, 1, 2, 3, 4, 5, 6, 7);
          bf4_t l0 = *(const bf4_t*)&h1loL[par][lm][cb];
          bf4_t l1 = *(const bf4_t*)&h1loL[par][lm][cb + 4];
          a1[kt][1] = __builtin_shufflevector(l0, l1, 0, 1, 2, 3, 4, 5, 6, 7);
        }
      }
    }
  }
#undef MF3
#undef MF

#pragma unroll
  for (int i = 0; i < 4; ++i)
    xh_out[(size_t)(r0 + 4 * lg + i) * HD + unit] = h1c[i];

  const float WaU = Wac[unit], WcU = Wac[64 + unit];
#pragma unroll
  for (int i = 0; i < 4; ++i) {
    float av = h1c[i] * WaU, cv = h1c[i] * WcU;
#pragma unroll
    for (int off = 1; off < 16; off <<= 1) {
      av += __shfl_xor(av, off, 64);
      cv += __shfl_xor(cv, off, 64);
    }
    if (lm == 0) {
      red[0][w][4 * lg + i] = av;
      red[1][w][4 * lg + i] = cv;
    }
  }
  __syncthreads();
  if (tid < MB) {
    a_out[r0 + tid] = red[0][0][tid] + red[0][1][tid] + red[0][2][tid] + red[0][3][tid];
    c_out[r0 + tid] = red[1][0][tid] + red[1][1][tid] + red[1][2][tid] + red[1][3][tid];
  }
}

// ---------------------------------------------------------------------------
// Kernel 2a: attention PARTIAL, 32 rows/block x 4 rows/thread.
// UM=1: mask sums from precomputed uint8 msum (16MB, exact).
// UM=0: legacy rel path (ws-size fallback).
// ---------------------------------------------------------------------------
template <int UM>
__global__ __launch_bounds__(256) void attn_part(
    const float* __restrict__ rel,
    const unsigned char* __restrict__ msum8,
    const float* __restrict__ xh,
    const float* __restrict__ aArr, const float* __restrict__ cArr,
    const float* __restrict__ bSc,
    float* __restrict__ part, int jsl, int lsp) {
  __shared__ float xhl[64][68];
  __shared__ float pbuf[ARB][64];
  __shared__ float cls[2048];

  const int tid = threadIdx.x;
  const int rg = tid >> 5;
  const int tk = tid & 31;
  const int bx = blockIdx.x;
  const int ib = bx >> lsp;
  const int js = bx & ((1 << lsp) - 1);
  const int jbeg = js * jsl;
  const int jend = (jbeg + jsl < NR) ? (jbeg + jsl) : NR;
  const int nch = (jend - jbeg + 63) >> 6;
  const float bb = bSc[0];

  int irow[4];
  float aib[4];
#pragma unroll
  for (int rr = 0; rr < 4; ++rr) {
    irow[rr] = ib * ARB + rg + 8 * rr;
    aib[rr] = aArr[irow[rr]] + bb;
  }

  for (int t = tid; t < jsl; t += 256)
    cls[t] = (jbeg + t < NR) ? cArr[jbeg + t] : 0.f;

  float pr[4][6];
  uchar2 pm[4];
#pragma unroll
  for (int rr = 0; rr < 4; ++rr) {
    if (UM) {
      pm[rr] = *(const uchar2*)&msum8[(size_t)irow[rr] * NR + jbeg + 2 * tk];
    } else {
      const float* rp = rel + (size_t)irow[rr] * (3 * NR) + (size_t)(jbeg + 2 * tk) * 3;
#pragma unroll
      for (int e = 0; e < 6; ++e) pr[rr][e] = rp[e];
    }
  }

  float m[4], s[4], acc0[4], acc1[4];
#pragma unroll
  for (int rr = 0; rr < 4; ++rr) { m[rr] = -3.0e38f; s[rr] = 0.f; acc0[rr] = 0.f; acc1[rr] = 0.f; }

  for (int c = 0; c < nch; ++c) {
    const int j0 = jbeg + c * 64;
    __syncthreads();
    {
      const int jj = tid >> 2, seg = tid & 3;
      const int j = j0 + jj;
      if (j < NR) {
        const float4* src = (const float4*)(xh + (size_t)j * 64 + seg * 16);
#pragma unroll
        for (int q = 0; q < 4; ++q) *(float4*)&xhl[jj][seg * 16 + 4 * q] = src[q];
      } else {
        float4 z = {0.f, 0.f, 0.f, 0.f};
#pragma unroll
        for (int q = 0; q < 4; ++q) *(float4*)&xhl[jj][seg * 16 + 4 * q] = z;
      }
    }

    const int jb = j0 + 2 * tk;
    const bool ok = (jb < jend);
    const int ci = c * 64 + 2 * tk;
    const float cl0 = cls[ci], cl1 = cls[ci + 1];

#pragma unroll
    for (int rr = 0; rr < 4; ++rr) {
      float msum0, msum1;
      if (UM) {
        msum0 = (float)pm[rr].x;
        msum1 = (float)pm[rr].y;
      } else {
        msum0 = pr[rr][0] + pr[rr][1] + pr[rr][2];
        msum1 = pr[rr][3] + pr[rr][4] + pr[rr][5];
      }
      float w0 = aib[rr] + cl0, w1 = aib[rr] + cl1;
      w0 = (w0 > 0.f) ? w0 : 0.01f * w0;
      w1 = (w1 > 0.f) ? w1 : 0.01f * w1;
      float v0 = (!ok) ? -3.0e37f : ((msum0 == 0.f) ? -1.0e6f : msum0 * w0);
      float v1 = (!ok) ? -3.0e37f : ((msum1 == 0.f) ? -1.0e6f : msum1 * w1);

      float lm2 = fmaxf(v0, v1);
#pragma unroll
      for (int off = 16; off; off >>= 1) lm2 = fmaxf(lm2, __shfl_xor(lm2, off, 32));
      const float mn = fmaxf(m[rr], lm2);
      const float f = __expf(m[rr] - mn);
      const float p0 = __expf(v0 - mn);
      const float p1 = __expf(v1 - mn);
      float ls = p0 + p1;
#pragma unroll
      for (int off = 16; off; off >>= 1) ls += __shfl_xor(ls, off, 32);
      s[rr] = s[rr] * f + ls;
      acc0[rr] *= f;
      acc1[rr] *= f;
      m[rr] = mn;
      pbuf[rg + 8 * rr][2 * tk] = p0;
      pbuf[rg + 8 * rr][2 * tk + 1] = p1;
    }

    if (c + 1 < nch) {
      const int jn = j0 + 64 + 2 * tk;
      if (jn < jend) {
#pragma unroll
        for (int rr = 0; rr < 4; ++rr) {
          if (UM) {
            pm[rr] = *(const uchar2*)&msum8[(size_t)irow[rr] * NR + jn];
          } else {
            const float* rp = rel + (size_t)irow[rr] * (3 * NR) + (size_t)jn * 3;
#pragma unroll
            for (int e = 0; e < 6; ++e) pr[rr][e] = rp[e];
          }
        }
      }
    }

    __syncthreads();

#pragma unroll 2
    for (int j4 = 0; j4 < 16; ++j4) {
      float4 pv0 = *(const float4*)&pbuf[rg][4 * j4];
      float4 pv1 = *(const float4*)&pbuf[rg + 8][4 * j4];
      float4 pv2 = *(const float4*)&pbuf[rg + 16][4 * j4];
      float4 pv3 = *(const float4*)&pbuf[rg + 24][4 * j4];
      float2 x0 = *(const float2*)&xhl[4 * j4 + 0][2 * tk];
      float2 x1 = *(const float2*)&xhl[4 * j4 + 1][2 * tk];
      float2 x2 = *(const float2*)&xhl[4 * j4 + 2][2 * tk];
      float2 x3 = *(const float2*)&xhl[4 * j4 + 3][2 * tk];
      acc0[0] = fmaf(pv0.x, x0.x, acc0[0]); acc1[0] = fmaf(pv0.x, x0.y, acc1[0]);
      acc0[0] = fmaf(pv0.y, x1.x, acc0[0]); acc1[0] = fmaf(pv0.y, x1.y, acc1[0]);
      acc0[0] = fmaf(pv0.z, x2.x, acc0[0]); acc1[0] = fmaf(pv0.z, x2.y, acc1[0]);
      acc0[0] = fmaf(pv0.w, x3.x, acc0[0]); acc1[0] = fmaf(pv0.w, x3.y, acc1[0]);
      acc0[1] = fmaf(pv1.x, x0.x, acc0[1]); acc1[1] = fmaf(pv1.x, x0.y, acc1[1]);
      acc0[1] = fmaf(pv1.y, x1.x, acc0[1]); acc1[1] = fmaf(pv1.y, x1.y, acc1[1]);
      acc0[1] = fmaf(pv1.z, x2.x, acc0[1]); acc1[1] = fmaf(pv1.z, x2.y, acc1[1]);
      acc0[1] = fmaf(pv1.w, x3.x, acc0[1]); acc1[1] = fmaf(pv1.w, x3.y, acc1[1]);
      acc0[2] = fmaf(pv2.x, x0.x, acc0[2]); acc1[2] = fmaf(pv2.x, x0.y, acc1[2]);
      acc0[2] = fmaf(pv2.y, x1.x, acc0[2]); acc1[2] = fmaf(pv2.y, x1.y, acc1[2]);
      acc0[2] = fmaf(pv2.z, x2.x, acc0[2]); acc1[2] = fmaf(pv2.z, x2.y, acc1[2]);
      acc0[2] = fmaf(pv2.w, x3.x, acc0[2]); acc1[2] = fmaf(pv2.w, x3.y, acc1[2]);
      acc0[3] = fmaf(pv3.x, x0.x, acc0[3]); acc1[3] = fmaf(pv3.x, x0.y, acc1[3]);
      acc0[3] = fmaf(pv3.y, x1.x, acc0[3]); acc1[3] = fmaf(pv3.y, x1.y, acc1[3]);
      acc0[3] = fmaf(pv3.z, x2.x, acc0[3]); acc1[3] = fmaf(pv3.z, x2.y, acc1[3]);
      acc0[3] = fmaf(pv3.w, x3.x, acc0[3]); acc1[3] = fmaf(pv3.w, x3.y, acc1[3]);
    }
  }

#pragma unroll
  for (int rr = 0; rr < 4; ++rr) {
    float* base = part + ((size_t)bx * ARB + rg + 8 * rr) * 66;
    if (tk == 0) { base[0] = m[rr]; base[1] = s[rr]; }
    base[2 + 2 * tk] = acc0[rr];
    base[3 + 2 * tk] = acc1[rr];
  }
}

// ---------------------------------------------------------------------------
// Kernel 2b: combine partials + final FC. NR/4 blocks x 256 (4 rows/block).
// ---------------------------------------------------------------------------
__global__ __launch_bounds__(256) void attn_combine(
    const float* __restrict__ part,
    const float* __restrict__ xh,
    const float* __restrict__ fcw, const float* __restrict__ fcb,
    float* __restrict__ pred, int nsplit) {
  const int tid = threadIdx.x;
  const int r = blockIdx.x * 4 + (tid >> 6);
  const int lane = tid & 63;
  const int ib = r / ARB, il = r % ARB;

  float mstar = -3.0e38f;
  for (int k = 0; k < nsplit; ++k) {
    const float* b = part + ((size_t)(ib * nsplit + k) * ARB + il) * 66;
    mstar = fmaxf(mstar, b[0]);
  }
  float sstar = 0.f, onum = 0.f;
  for (int k = 0; k < nsplit; ++k) {
    const float* b = part + ((size_t)(ib * nsplit + k) * ARB + il) * 66;
    const float wk = __expf(b[0] - mstar);
    sstar = fmaf(wk, b[1], sstar);
    onum = fmaf(wk, b[2 + lane], onum);
  }
  const float o = onum / sstar;
  float p = fcw[lane] * xh[(size_t)r * HD + lane] + fcw[64 + lane] * o;
#pragma unroll
  for (int off = 32; off; off >>= 1) p += __shfl_xor(p, off, 64);
  if (lane == 0) pred[r] = p + fcb[0];
}

extern "C" void kernel_launch(void* const* d_in, const int* in_sizes, int n_in,
                              void* d_out, int out_size, void* d_ws, size_t ws_size,
                              hipStream_t stream) {
  const float* x    = (const float*)d_in[0];
  const float* rel  = (const float*)d_in[1];
  const float* Wih0 = (const float*)d_in[2];
  const float* Whh0 = (const float*)d_in[3];
  const float* bih0 = (const float*)d_in[4];
  const float* bhh0 = (const float*)d_in[5];
  const float* Wih1 = (const float*)d_in[6];
  const float* Whh1 = (const float*)d_in[7];
  const float* bih1 = (const float*)d_in[8];
  const float* bhh1 = (const float*)d_in[9];
  const float* Wac  = (const float*)d_in[10];
  const float* bSc  = (const float*)d_in[11];
  const float* fcw  = (const float*)d_in[12];
  const float* fcb  = (const float*)d_in[13];

  float* xh = (float*)d_ws;
  float* aA = xh + (size_t)NR * HD;
  float* cA = aA + NR;
  float* part = cA + NR;
  float* pred = (float*)d_out;

  // workspace ladder: prefer msum (16MB uint8) + largest nsplit that fits.
  const size_t headF = (size_t)NR * HD + 2 * NR;       // floats
  const size_t msumB = (size_t)NR * NR;                // bytes
  auto needB = [&](int ns, bool um) {
    return (headF + (size_t)(NR / ARB) * ns * ARB * 66) * 4 + (um ? msumB : 0);
  };
  bool use_msum = true;
  int nsplit = 8, lsp = 3;
  if (needB(8, true) > ws_size) {
    if (needB(4, true) <= ws_size) { nsplit = 4; lsp = 2; }
    else if (needB(2, true) <= ws_size) { nsplit = 2; lsp = 1; }
    else {
      use_msum = false;
      if (needB(8, false) <= ws_size) { nsplit = 8; lsp = 3; }
      else { nsplit = 4; lsp = 2; }
    }
  }
  const int jsl = NR / nsplit;
  unsigned char* msum8 =
      (unsigned char*)(part + (size_t)(NR / ARB) * nsplit * ARB * 66);

  if (use_msum) {
    msum_kernel<<<2048, 256, 0, stream>>>(rel, msum8);
  }
  gru_mfma<<<NR / MB, 256, 0, stream>>>(x, Wih0, Whh0, bih0, bhh0, Wih1, Whh1,
                                        bih1, bhh1, Wac, xh, aA, cA);
  if (use_msum) {
    attn_part<1><<<(NR / ARB) * nsplit, 256, 0, stream>>>(
        rel, msum8, xh, aA, cA, bSc, part, jsl, lsp);
  } else {
    attn_part<0><<<(NR / ARB) * nsplit, 256, 0, stream>>>(
        rel, msum8, xh, aA, cA, bSc, part, jsl, lsp);
  }
  attn_combine<<<NR / 4, 256, 0, stream>>>(part, xh, fcw, fcb, pred, nsplit);
}

// Round 17
// 197.723 us; speedup vs baseline: 1.0617x; 1.0617x over previous
//
#include <hip/hip_runtime.h>

#define NR 4000
#define TS 60
#define DF 6
#define HD 64
#define MB 16    // rows per GRU block
#define ARB 32   // rows per attn block

typedef __attribute__((ext_vector_type(8))) short bf8_t;
typedef __attribute__((ext_vector_type(4))) short bf4_t;
typedef __attribute__((ext_vector_type(4))) float f32x4;

__device__ __forceinline__ float sigf(float x) { return 1.0f / (1.0f + __expf(-x)); }
__device__ __forceinline__ float tanhfast(float x) { return 1.0f - 2.0f / (1.0f + __expf(2.0f * x)); }

__device__ __forceinline__ unsigned short f2bf(float v) {
  union { float f; unsigned u; } x; x.f = v;
  unsigned r = (x.u + 0x7fffu + ((x.u >> 16) & 1u)) >> 16;
  return (unsigned short)r;
}
__device__ __forceinline__ float bf2f(unsigned short h) {
  union { unsigned u; float f; } y; y.u = ((unsigned)h) << 16; return y.f;
}
__device__ __forceinline__ void split8(const float* v, bf8_t& hi, bf8_t& lo) {
#pragma unroll
  for (int j = 0; j < 8; ++j) {
    unsigned short h = f2bf(v[j]);
    float rem = v[j] - bf2f(h);
    hi[j] = (short)h;
    lo[j] = (short)f2bf(rem);
  }
}

// ---------------------------------------------------------------------------
// Kernel 1: fused 2-layer GRU via split-bf16 MFMA — round-9/11 proven (122us).
// Failed alternatives: (256,2) spills (r6); 8-wave dup-rows (r10); msum
// co-residency (r14); setprio (r15); standalone msum precompute (r16: msum
// has zero reuse -> strictly extra traffic).
// ---------------------------------------------------------------------------
__global__ __launch_bounds__(256, 1) void gru_mfma(
    const float* __restrict__ x,
    const float* __restrict__ Wih0, const float* __restrict__ Whh0,
    const float* __restrict__ bih0, const float* __restrict__ bhh0,
    const float* __restrict__ Wih1, const float* __restrict__ Whh1,
    const float* __restrict__ bih1, const float* __restrict__ bhh1,
    const float* __restrict__ Wac,
    float* __restrict__ xh_out, float* __restrict__ a_out, float* __restrict__ c_out) {
  __shared__ float xldsT[TS][MB][12];
  __shared__ __align__(16) unsigned short h0hiL[2][16][76];
  __shared__ __align__(16) unsigned short h0loL[2][16][76];
  __shared__ __align__(16) unsigned short h1hiL[2][16][76];
  __shared__ __align__(16) unsigned short h1loL[2][16][76];
  __shared__ float red[2][4][MB];

  const int tid = threadIdx.x;
  const int w = tid >> 6;
  const int lane = tid & 63;
  const int lg = lane >> 4;
  const int lm = lane & 15;
  const int unit = w * 16 + lm;
  const int r0 = blockIdx.x * MB;

  for (int idx = tid; idx < MB * 360; idx += 256) {
    int rr = idx / 360, cc = idx - rr * 360;
    int f = cc / 60, t = cc - f * 60;
    xldsT[t][rr][f] = x[(size_t)r0 * 360 + idx];
  }

  bf8_t wB[3][3][2][2];
  {
    const float* mats[3] = {Whh0, Wih1, Whh1};
#pragma unroll
    for (int m = 0; m < 3; ++m)
#pragma unroll
      for (int g = 0; g < 3; ++g)
#pragma unroll
        for (int kt = 0; kt < 2; ++kt) {
          const float* src = mats[m] + (size_t)(g * 64 + unit) * 64 + kt * 32 + 8 * lg;
          float v[8];
          *(float4*)&v[0] = *(const float4*)&src[0];
          *(float4*)&v[4] = *(const float4*)&src[4];
          split8(v, wB[m][g][kt][0], wB[m][g][kt][1]);
        }
  }
  float wih0g[3][DF];
#pragma unroll
  for (int g = 0; g < 3; ++g)
#pragma unroll
    for (int f = 0; f < DF; ++f)
      wih0g[g][f] = Wih0[(size_t)(g * 64 + unit) * DF + f];

  const float bi0r = bih0[unit], bi0z = bih0[64 + unit], bi0n = bih0[128 + unit];
  const float bh0r = bhh0[unit], bh0z = bhh0[64 + unit], bh0n = bhh0[128 + unit];
  const float c1R = bih1[unit] + bhh1[unit];
  const float c1Z = bih1[64 + unit] + bhh1[64 + unit];
  const float b1xn = bih1[128 + unit], b1hn = bhh1[128 + unit];

  bf8_t a0[2][2], a1[2][2];
  bf8_t zf = {};
#pragma unroll
  for (int kt = 0; kt < 2; ++kt)
#pragma unroll
    for (int h = 0; h < 2; ++h) { a0[kt][h] = zf; a1[kt][h] = zf; }
  float h0c[4] = {0.f, 0.f, 0.f, 0.f};
  float h1c[4] = {0.f, 0.f, 0.f, 0.f};

  __syncthreads();

#define MF(acc, A, B) acc = __builtin_amdgcn_mfma_f32_16x16x32_bf16(A, B, acc, 0, 0, 0)
#define MF3(acc, Af, Bf) do { \
    MF(acc, Af[0], Bf[0]); MF(acc, Af[0], Bf[1]); MF(acc, Af[1], Bf[0]); } while (0)

  for (int p = 0; p <= TS; ++p) {
    const bool doL0 = (p < TS);
    const bool doL1 = (p >= 1);
    const int par = p & 1;
    f32x4 aR, aZ, aN;
    float xn0[4];
    if (doL0) {
#pragma unroll
      for (int i = 0; i < 4; ++i) {
        const int row = 4 * lg + i;
        const float* xb = &xldsT[p][row][0];
        float4 x4 = *(const float4*)xb;
        float2 x2 = *(const float2*)(xb + 4);
        float sr = bi0r, sz = bi0z, sn = bi0n;
        sr = fmaf(wih0g[0][0], x4.x, sr); sz = fmaf(wih0g[1][0], x4.x, sz); sn = fmaf(wih0g[2][0], x4.x, sn);
        sr = fmaf(wih0g[0][1], x4.y, sr); sz = fmaf(wih0g[1][1], x4.y, sz); sn = fmaf(wih0g[2][1], x4.y, sn);
        sr = fmaf(wih0g[0][2], x4.z, sr); sz = fmaf(wih0g[1][2], x4.z, sz); sn = fmaf(wih0g[2][2], x4.z, sn);
        sr = fmaf(wih0g[0][3], x4.w, sr); sz = fmaf(wih0g[1][3], x4.w, sz); sn = fmaf(wih0g[2][3], x4.w, sn);
        sr = fmaf(wih0g[0][4], x2.x, sr); sz = fmaf(wih0g[1][4], x2.x, sz); sn = fmaf(wih0g[2][4], x2.x, sn);
        sr = fmaf(wih0g[0][5], x2.y, sr); sz = fmaf(wih0g[1][5], x2.y, sz); sn = fmaf(wih0g[2][5], x2.y, sn);
        aR[i] = sr + bh0r;
        aZ[i] = sz + bh0z;
        aN[i] = bh0n;
        xn0[i] = sn;
      }
#pragma unroll
      for (int kt = 0; kt < 2; ++kt) {
        MF3(aR, a0[kt], wB[0][0][kt]);
        MF3(aZ, a0[kt], wB[0][1][kt]);
        MF3(aN, a0[kt], wB[0][2][kt]);
      }
    }
    f32x4 R1, Z1, XN, HN;
    if (doL1) {
#pragma unroll
      for (int i = 0; i < 4; ++i) { R1[i] = c1R; Z1[i] = c1Z; XN[i] = b1xn; HN[i] = b1hn; }
#pragma unroll
      for (int kt = 0; kt < 2; ++kt) {
        MF3(R1, a0[kt], wB[1][0][kt]);
        MF3(Z1, a0[kt], wB[1][1][kt]);
        MF3(XN, a0[kt], wB[1][2][kt]);
        MF3(R1, a1[kt], wB[2][0][kt]);
        MF3(Z1, a1[kt], wB[2][1][kt]);
        MF3(HN, a1[kt], wB[2][2][kt]);
      }
    }
    if (doL0) {
#pragma unroll
      for (int i = 0; i < 4; ++i) {
        float r = sigf(aR[i]);
        float z = sigf(aZ[i]);
        float n = tanhfast(xn0[i] + r * aN[i]);
        h0c[i] = n + z * (h0c[i] - n);
        const int row = 4 * lg + i;
        unsigned u = __float_as_uint(h0c[i]);
        h0hiL[par][row][unit] = (unsigned short)(u >> 16);
        float lo = h0c[i] - __uint_as_float(u & 0xffff0000u);
        h0loL[par][row][unit] = (unsigned short)(__float_as_uint(lo) >> 16);
      }
    }
    if (doL1) {
#pragma unroll
      for (int i = 0; i < 4; ++i) {
        float r = sigf(R1[i]);
        float z = sigf(Z1[i]);
        float n = tanhfast(XN[i] + r * HN[i]);
        h1c[i] = n + z * (h1c[i] - n);
      }
      if (p < TS) {
#pragma unroll
        for (int i = 0; i < 4; ++i) {
          const int row = 4 * lg + i;
          unsigned u = __float_as_uint(h1c[i]);
          h1hiL[par][row][unit] = (unsigned short)(u >> 16);
          float lo = h1c[i] - __uint_as_float(u & 0xffff0000u);
          h1loL[par][row][unit] = (unsigned short)(__float_as_uint(lo) >> 16);
        }
      }
    }
    __syncthreads();
    if (p < TS) {
#pragma unroll
      for (int kt = 0; kt < 2; ++kt) {
        const int cb = kt * 32 + 8 * lg;
        bf4_t u0 = *(const bf4_t*)&h0hiL[par][lm][cb];
        bf4_t u1 = *(const bf4_t*)&h0hiL[par][lm][cb + 4];
        a0[kt][0] = __builtin_shufflevector(u0, u1, 0, 1, 2, 3, 4, 5, 6, 7);
        bf4_t l0 = *(const bf4_t*)&h0loL[par][lm][cb];
        bf4_t l1 = *(const bf4_t*)&h0loL[par][lm][cb + 4];
        a0[kt][1] = __builtin_shufflevector(l0, l1, 0, 1, 2, 3, 4, 5, 6, 7);
      }
      if (p >= 1) {
#pragma unroll
        for (int kt = 0; kt < 2; ++kt) {
          const int cb = kt * 32 + 8 * lg;
          bf4_t u0 = *(const bf4_t*)&h1hiL[par][lm][cb];
          bf4_t u1 = *(const bf4_t*)&h1hiL[par][lm][cb + 4];
          a1[kt][0] = __builtin_shufflevector(u0, u1, 0, 1, 2, 3, 4, 5, 6, 7);
          bf4_t l0 = *(const bf4_t*)&h1loL[par][lm][cb];
          bf4_t l1 = *(const bf4_t*)&h1loL[par][lm][cb + 4];
          a1[kt][1] = __builtin_shufflevector(l0, l1, 0, 1, 2, 3, 4, 5, 6, 7);
        }
      }
    }
  }
#undef MF3
#undef MF

#pragma unroll
  for (int i = 0; i < 4; ++i)
    xh_out[(size_t)(r0 + 4 * lg + i) * HD + unit] = h1c[i];

  const float WaU = Wac[unit], WcU = Wac[64 + unit];
#pragma unroll
  for (int i = 0; i < 4; ++i) {
    float av = h1c[i] * WaU, cv = h1c[i] * WcU;
#pragma unroll
    for (int off = 1; off < 16; off <<= 1) {
      av += __shfl_xor(av, off, 64);
      cv += __shfl_xor(cv, off, 64);
    }
    if (lm == 0) {
      red[0][w][4 * lg + i] = av;
      red[1][w][4 * lg + i] = cv;
    }
  }
  __syncthreads();
  if (tid < MB) {
    a_out[r0 + tid] = red[0][0][tid] + red[0][1][tid] + red[0][2][tid] + red[0][3][tid];
    c_out[r0 + tid] = red[1][0][tid] + red[1][1][tid] + red[1][2][tid] + red[1][3][tid];
  }
}

// ---------------------------------------------------------------------------
// Kernel 2a (nsplit=8 path): attention PARTIAL with LDS-staged rel reads.
// Per chunk: block cooperatively stages rel[32 rows][64 pairs][3] (24KB) as
// 1536 lane-consecutive float4 loads (768B-contiguous runs -> ~3x fewer
// L1/TA granules than the old 24B/lane-strided per-thread loads, which
// capped rel streaming at ~3.8 TB/s). Scores read relL via stride-6-dword
// b64 (2-way bank = free). jsl fixed at 500 (NR/8).
// ---------------------------------------------------------------------------
__global__ __launch_bounds__(256) void attn_part_lds(
    const float* __restrict__ rel,
    const float* __restrict__ xh,
    const float* __restrict__ aArr, const float* __restrict__ cArr,
    const float* __restrict__ bSc,
    float* __restrict__ part) {
  __shared__ float xhl[64][68];     // 17.4KB
  __shared__ float pbuf[ARB][64];   // 8KB
  __shared__ float cls[512];        // 2KB
  __shared__ float relL[32][200];   // 25.6KB (192 + 8 pad)

  const int tid = threadIdx.x;
  const int rg = tid >> 5;
  const int tk = tid & 31;
  const int bx = blockIdx.x;
  const int ib = bx >> 3;
  const int js = bx & 7;
  const int jsl = NR / 8;           // 500
  const int jbeg = js * jsl;
  const int jend = jbeg + jsl;      // 4000 = 8*500 exactly
  const float bb = bSc[0];

  int irow[4];
  float aib[4];
#pragma unroll
  for (int rr = 0; rr < 4; ++rr) {
    irow[rr] = ib * ARB + rg + 8 * rr;
    aib[rr] = aArr[irow[rr]] + bb;
  }

  for (int t = tid; t < 512; t += 256)
    cls[t] = (t < jsl) ? cArr[jbeg + t] : 0.f;

  float m[4], s[4], acc0[4], acc1[4];
#pragma unroll
  for (int rr = 0; rr < 4; ++rr) { m[rr] = -3.0e38f; s[rr] = 0.f; acc0[rr] = 0.f; acc1[rr] = 0.f; }

  for (int c = 0; c < 8; ++c) {
    const int j0 = jbeg + c * 64;
    __syncthreads();  // previous chunk fully consumed
    // ---- stage xh chunk (padded, conflict-free) ----
    {
      const int jj = tid >> 2, seg = tid & 3;
      const int j = j0 + jj;
      if (j < NR) {
        const float4* src = (const float4*)(xh + (size_t)j * 64 + seg * 16);
#pragma unroll
        for (int q = 0; q < 4; ++q) *(float4*)&xhl[jj][seg * 16 + 4 * q] = src[q];
      } else {
        float4 z = {0.f, 0.f, 0.f, 0.f};
#pragma unroll
        for (int q = 0; q < 4; ++q) *(float4*)&xhl[jj][seg * 16 + 4 * q] = z;
      }
    }
    // ---- stage rel chunk: 32 rows x 192 floats, lane-consecutive float4 ----
#pragma unroll
    for (int k = 0; k < 6; ++k) {
      const int fidx = k * 256 + tid;      // 0..1535
      const int sg = fidx / 48;            // row-in-block 0..31
      const int q = fidx - sg * 48;        // float4 within row 0..47
      int fo = j0 * 3 + 4 * q;             // row-local float offset
      if (fo > 12000 - 4) fo = 0;          // tail clamp (masked by ok below)
      const float4 v = *(const float4*)(rel + (size_t)(ib * 32 + sg) * 12000 + fo);
      *(float4*)&relL[sg][4 * q] = v;
    }
    __syncthreads();  // xhl + relL ready

    const int jb = j0 + 2 * tk;
    const bool ok = (jb < jend);
    const int ci = c * 64 + 2 * tk;
    const float cl0 = cls[ci], cl1 = cls[ci + 1];

#pragma unroll
    for (int rr = 0; rr < 4; ++rr) {
      const int qp = rg + 8 * rr;
      float2 f0 = *(const float2*)&relL[qp][6 * tk];
      float2 f1 = *(const float2*)&relL[qp][6 * tk + 2];
      float2 f2 = *(const float2*)&relL[qp][6 * tk + 4];
      float msum0 = f0.x + f0.y + f1.x;
      float msum1 = f1.y + f2.x + f2.y;
      float w0 = aib[rr] + cl0, w1 = aib[rr] + cl1;
      w0 = (w0 > 0.f) ? w0 : 0.01f * w0;
      w1 = (w1 > 0.f) ? w1 : 0.01f * w1;
      float v0 = (!ok) ? -3.0e37f : ((msum0 == 0.f) ? -1.0e6f : msum0 * w0);
      float v1 = (!ok) ? -3.0e37f : ((msum1 == 0.f) ? -1.0e6f : msum1 * w1);

      float lm2 = fmaxf(v0, v1);
#pragma unroll
      for (int off = 16; off; off >>= 1) lm2 = fmaxf(lm2, __shfl_xor(lm2, off, 32));
      const float mn = fmaxf(m[rr], lm2);
      const float f = __expf(m[rr] - mn);
      const float p0 = __expf(v0 - mn);
      const float p1 = __expf(v1 - mn);
      float ls = p0 + p1;
#pragma unroll
      for (int off = 16; off; off >>= 1) ls += __shfl_xor(ls, off, 32);
      s[rr] = s[rr] * f + ls;
      acc0[rr] *= f;
      acc1[rr] *= f;
      m[rr] = mn;
      pbuf[rg + 8 * rr][2 * tk] = p0;
      pbuf[rg + 8 * rr][2 * tk + 1] = p1;  // same half-wave writes & reads
    }

#pragma unroll 2
    for (int j4 = 0; j4 < 16; ++j4) {
      float4 pv0 = *(const float4*)&pbuf[rg][4 * j4];
      float4 pv1 = *(const float4*)&pbuf[rg + 8][4 * j4];
      float4 pv2 = *(const float4*)&pbuf[rg + 16][4 * j4];
      float4 pv3 = *(const float4*)&pbuf[rg + 24][4 * j4];
      float2 x0 = *(const float2*)&xhl[4 * j4 + 0][2 * tk];
      float2 x1 = *(const float2*)&xhl[4 * j4 + 1][2 * tk];
      float2 x2 = *(const float2*)&xhl[4 * j4 + 2][2 * tk];
      float2 x3 = *(const float2*)&xhl[4 * j4 + 3][2 * tk];
      acc0[0] = fmaf(pv0.x, x0.x, acc0[0]); acc1[0] = fmaf(pv0.x, x0.y, acc1[0]);
      acc0[0] = fmaf(pv0.y, x1.x, acc0[0]); acc1[0] = fmaf(pv0.y, x1.y, acc1[0]);
      acc0[0] = fmaf(pv0.z, x2.x, acc0[0]); acc1[0] = fmaf(pv0.z, x2.y, acc1[0]);
      acc0[0] = fmaf(pv0.w, x3.x, acc0[0]); acc1[0] = fmaf(pv0.w, x3.y, acc1[0]);
      acc0[1] = fmaf(pv1.x, x0.x, acc0[1]); acc1[1] = fmaf(pv1.x, x0.y, acc1[1]);
      acc0[1] = fmaf(pv1.y, x1.x, acc0[1]); acc1[1] = fmaf(pv1.y, x1.y, acc1[1]);
      acc0[1] = fmaf(pv1.z, x2.x, acc0[1]); acc1[1] = fmaf(pv1.z, x2.y, acc1[1]);
      acc0[1] = fmaf(pv1.w, x3.x, acc0[1]); acc1[1] = fmaf(pv1.w, x3.y, acc1[1]);
      acc0[2] = fmaf(pv2.x, x0.x, acc0[2]); acc1[2] = fmaf(pv2.x, x0.y, acc1[2]);
      acc0[2] = fmaf(pv2.y, x1.x, acc0[2]); acc1[2] = fmaf(pv2.y, x1.y, acc1[2]);
      acc0[2] = fmaf(pv2.z, x2.x, acc0[2]); acc1[2] = fmaf(pv2.z, x2.y, acc1[2]);
      acc0[2] = fmaf(pv2.w, x3.x, acc0[2]); acc1[2] = fmaf(pv2.w, x3.y, acc1[2]);
      acc0[3] = fmaf(pv3.x, x0.x, acc0[3]); acc1[3] = fmaf(pv3.x, x0.y, acc1[3]);
      acc0[3] = fmaf(pv3.y, x1.x, acc0[3]); acc1[3] = fmaf(pv3.y, x1.y, acc1[3]);
      acc0[3] = fmaf(pv3.z, x2.x, acc0[3]); acc1[3] = fmaf(pv3.z, x2.y, acc1[3]);
      acc0[3] = fmaf(pv3.w, x3.x, acc0[3]); acc1[3] = fmaf(pv3.w, x3.y, acc1[3]);
    }
  }

#pragma unroll
  for (int rr = 0; rr < 4; ++rr) {
    float* base = part + ((size_t)bx * ARB + rg + 8 * rr) * 66;
    if (tk == 0) { base[0] = m[rr]; base[1] = s[rr]; }
    base[2 + 2 * tk] = acc0[rr];
    base[3 + 2 * tk] = acc1[rr];
  }
}

// ---------------------------------------------------------------------------
// Kernel 2a-fallback (nsplit != 8): round-11 proven rel-direct version.
// ---------------------------------------------------------------------------
__global__ __launch_bounds__(256) void attn_part_direct(
    const float* __restrict__ rel,
    const float* __restrict__ xh,
    const float* __restrict__ aArr, const float* __restrict__ cArr,
    const float* __restrict__ bSc,
    float* __restrict__ part, int jsl, int lsp) {
  __shared__ float xhl[64][68];
  __shared__ float pbuf[ARB][64];
  __shared__ float cls[2048];

  const int tid = threadIdx.x;
  const int rg = tid >> 5;
  const int tk = tid & 31;
  const int bx = blockIdx.x;
  const int ib = bx >> lsp;
  const int js = bx & ((1 << lsp) - 1);
  const int jbeg = js * jsl;
  const int jend = (jbeg + jsl < NR) ? (jbeg + jsl) : NR;
  const int nch = (jend - jbeg + 63) >> 6;
  const float bb = bSc[0];

  int irow[4];
  float aib[4];
#pragma unroll
  for (int rr = 0; rr < 4; ++rr) {
    irow[rr] = ib * ARB + rg + 8 * rr;
    aib[rr] = aArr[irow[rr]] + bb;
  }

  for (int t = tid; t < jsl; t += 256)
    cls[t] = (jbeg + t < NR) ? cArr[jbeg + t] : 0.f;

  float pr[4][6];
#pragma unroll
  for (int rr = 0; rr < 4; ++rr) {
    const float* rp = rel + (size_t)irow[rr] * (3 * NR) + (size_t)(jbeg + 2 * tk) * 3;
#pragma unroll
    for (int e = 0; e < 6; ++e) pr[rr][e] = rp[e];
  }

  float m[4], s[4], acc0[4], acc1[4];
#pragma unroll
  for (int rr = 0; rr < 4; ++rr) { m[rr] = -3.0e38f; s[rr] = 0.f; acc0[rr] = 0.f; acc1[rr] = 0.f; }

  for (int c = 0; c < nch; ++c) {
    const int j0 = jbeg + c * 64;
    __syncthreads();
    {
      const int jj = tid >> 2, seg = tid & 3;
      const int j = j0 + jj;
      if (j < NR) {
        const float4* src = (const float4*)(xh + (size_t)j * 64 + seg * 16);
#pragma unroll
        for (int q = 0; q < 4; ++q) *(float4*)&xhl[jj][seg * 16 + 4 * q] = src[q];
      } else {
        float4 z = {0.f, 0.f, 0.f, 0.f};
#pragma unroll
        for (int q = 0; q < 4; ++q) *(float4*)&xhl[jj][seg * 16 + 4 * q] = z;
      }
    }

    const int jb = j0 + 2 * tk;
    const bool ok = (jb < jend);
    const int ci = c * 64 + 2 * tk;
    const float cl0 = cls[ci], cl1 = cls[ci + 1];

#pragma unroll
    for (int rr = 0; rr < 4; ++rr) {
      float msum0 = pr[rr][0] + pr[rr][1] + pr[rr][2];
      float msum1 = pr[rr][3] + pr[rr][4] + pr[rr][5];
      float w0 = aib[rr] + cl0, w1 = aib[rr] + cl1;
      w0 = (w0 > 0.f) ? w0 : 0.01f * w0;
      w1 = (w1 > 0.f) ? w1 : 0.01f * w1;
      float v0 = (!ok) ? -3.0e37f : ((msum0 == 0.f) ? -1.0e6f : msum0 * w0);
      float v1 = (!ok) ? -3.0e37f : ((msum1 == 0.f) ? -1.0e6f : msum1 * w1);

      float lm2 = fmaxf(v0, v1);
#pragma unroll
      for (int off = 16; off; off >>= 1) lm2 = fmaxf(lm2, __shfl_xor(lm2, off, 32));
      const float mn = fmaxf(m[rr], lm2);
      const float f = __expf(m[rr] - mn);
      const float p0 = __expf(v0 - mn);
      const float p1 = __expf(v1 - mn);
      float ls = p0 + p1;
#pragma unroll
      for (int off = 16; off; off >>= 1) ls += __shfl_xor(ls, off, 32);
      s[rr] = s[rr] * f + ls;
      acc0[rr] *= f;
      acc1[rr] *= f;
      m[rr] = mn;
      pbuf[rg + 8 * rr][2 * tk] = p0;
      pbuf[rg + 8 * rr][2 * tk + 1] = p1;
    }

    if (c + 1 < nch) {
      const int jn = j0 + 64 + 2 * tk;
      if (jn < jend) {
#pragma unroll
        for (int rr = 0; rr < 4; ++rr) {
          const float* rp = rel + (size_t)irow[rr] * (3 * NR) + (size_t)jn * 3;
#pragma unroll
          for (int e = 0; e < 6; ++e) pr[rr][e] = rp[e];
        }
      }
    }

    __syncthreads();

#pragma unroll 2
    for (int j4 = 0; j4 < 16; ++j4) {
      float4 pv0 = *(const float4*)&pbuf[rg][4 * j4];
      float4 pv1 = *(const float4*)&pbuf[rg + 8][4 * j4];
      float4 pv2 = *(const float4*)&pbuf[rg + 16][4 * j4];
      float4 pv3 = *(const float4*)&pbuf[rg + 24][4 * j4];
      float2 x0 = *(const float2*)&xhl[4 * j4 + 0][2 * tk];
      float2 x1 = *(const float2*)&xhl[4 * j4 + 1][2 * tk];
      float2 x2 = *(const float2*)&xhl[4 * j4 + 2][2 * tk];
      float2 x3 = *(const float2*)&xhl[4 * j4 + 3][2 * tk];
      acc0[0] = fmaf(pv0.x, x0.x, acc0[0]); acc1[0] = fmaf(pv0.x, x0.y, acc1[0]);
      acc0[0] = fmaf(pv0.y, x1.x, acc0[0]); acc1[0] = fmaf(pv0.y, x1.y, acc1[0]);
      acc0[0] = fmaf(pv0.z, x2.x, acc0[0]); acc1[0] = fmaf(pv0.z, x2.y, acc1[0]);
      acc0[0] = fmaf(pv0.w, x3.x, acc0[0]); acc1[0] = fmaf(pv0.w, x3.y, acc1[0]);
      acc0[1] = fmaf(pv1.x, x0.x, acc0[1]); acc1[1] = fmaf(pv1.x, x0.y, acc1[1]);
      acc0[1] = fmaf(pv1.y, x1.x, acc0[1]); acc1[1] = fmaf(pv1.y, x1.y, acc1[1]);
      acc0[1] = fmaf(pv1.z, x2.x, acc0[1]); acc1[1] = fmaf(pv1.z, x2.y, acc1[1]);
      acc0[1] = fmaf(pv1.w, x3.x, acc0[1]); acc1[1] = fmaf(pv1.w, x3.y, acc1[1]);
      acc0[2] = fmaf(pv2.x, x0.x, acc0[2]); acc1[2] = fmaf(pv2.x, x0.y, acc1[2]);
      acc0[2] = fmaf(pv2.y, x1.x, acc0[2]); acc1[2] = fmaf(pv2.y, x1.y, acc1[2]);
      acc0[2] = fmaf(pv2.z, x2.x, acc0[2]); acc1[2] = fmaf(pv2.z, x2.y, acc1[2]);
      acc0[2] = fmaf(pv2.w, x3.x, acc0[2]); acc1[2] = fmaf(pv2.w, x3.y, acc1[2]);
      acc0[3] = fmaf(pv3.x, x0.x, acc0[3]); acc1[3] = fmaf(pv3.x, x0.y, acc1[3]);
      acc0[3] = fmaf(pv3.y, x1.x, acc0[3]); acc1[3] = fmaf(pv3.y, x1.y, acc1[3]);
      acc0[3] = fmaf(pv3.z, x2.x, acc0[3]); acc1[3] = fmaf(pv3.z, x2.y, acc1[3]);
      acc0[3] = fmaf(pv3.w, x3.x, acc0[3]); acc1[3] = fmaf(pv3.w, x3.y, acc1[3]);
    }
  }

#pragma unroll
  for (int rr = 0; rr < 4; ++rr) {
    float* base = part + ((size_t)bx * ARB + rg + 8 * rr) * 66;
    if (tk == 0) { base[0] = m[rr]; base[1] = s[rr]; }
    base[2 + 2 * tk] = acc0[rr];
    base[3 + 2 * tk] = acc1[rr];
  }
}

// ---------------------------------------------------------------------------
// Kernel 2b: combine partials + final FC. NR/4 blocks x 256 (4 rows/block).
// ---------------------------------------------------------------------------
__global__ __launch_bounds__(256) void attn_combine(
    const float* __restrict__ part,
    const float* __restrict__ xh,
    const float* __restrict__ fcw, const float* __restrict__ fcb,
    float* __restrict__ pred, int nsplit) {
  const int tid = threadIdx.x;
  const int r = blockIdx.x * 4 + (tid >> 6);
  const int lane = tid & 63;
  const int ib = r / ARB, il = r % ARB;

  float mstar = -3.0e38f;
  for (int k = 0; k < nsplit; ++k) {
    const float* b = part + ((size_t)(ib * nsplit + k) * ARB + il) * 66;
    mstar = fmaxf(mstar, b[0]);
  }
  float sstar = 0.f, onum = 0.f;
  for (int k = 0; k < nsplit; ++k) {
    const float* b = part + ((size_t)(ib * nsplit + k) * ARB + il) * 66;
    const float wk = __expf(b[0] - mstar);
    sstar = fmaf(wk, b[1], sstar);
    onum = fmaf(wk, b[2 + lane], onum);
  }
  const float o = onum / sstar;
  float p = fcw[lane] * xh[(size_t)r * HD + lane] + fcw[64 + lane] * o;
#pragma unroll
  for (int off = 32; off; off >>= 1) p += __shfl_xor(p, off, 64);
  if (lane == 0) pred[r] = p + fcb[0];
}

extern "C" void kernel_launch(void* const* d_in, const int* in_sizes, int n_in,
                              void* d_out, int out_size, void* d_ws, size_t ws_size,
                              hipStream_t stream) {
  const float* x    = (const float*)d_in[0];
  const float* rel  = (const float*)d_in[1];
  const float* Wih0 = (const float*)d_in[2];
  const float* Whh0 = (const float*)d_in[3];
  const float* bih0 = (const float*)d_in[4];
  const float* bhh0 = (const float*)d_in[5];
  const float* Wih1 = (const float*)d_in[6];
  const float* Whh1 = (const float*)d_in[7];
  const float* bih1 = (const float*)d_in[8];
  const float* bhh1 = (const float*)d_in[9];
  const float* Wac  = (const float*)d_in[10];
  const float* bSc  = (const float*)d_in[11];
  const float* fcw  = (const float*)d_in[12];
  const float* fcb  = (const float*)d_in[13];

  float* xh = (float*)d_ws;
  float* aA = xh + (size_t)NR * HD;
  float* cA = aA + NR;
  float* part = cA + NR;
  float* pred = (float*)d_out;

  const size_t headF = (size_t)NR * HD + 2 * NR;  // floats
  auto needB = [&](int ns) {
    return (headF + (size_t)(NR / ARB) * ns * ARB * 66) * 4;
  };
  int nsplit = 8, lsp = 3;
  if (needB(8) > ws_size) { nsplit = 4; lsp = 2; }
  const int jsl = NR / nsplit;

  gru_mfma<<<NR / MB, 256, 0, stream>>>(x, Wih0, Whh0, bih0, bhh0, Wih1, Whh1,
                                        bih1, bhh1, Wac, xh, aA, cA);
  if (nsplit == 8) {
    attn_part_lds<<<(NR / ARB) * 8, 256, 0, stream>>>(rel, xh, aA, cA, bSc, part);
  } else {
    attn_part_direct<<<(NR / ARB) * nsplit, 256, 0, stream>>>(
        rel, xh, aA, cA, bSc, part, jsl, lsp);
  }
  attn_combine<<<NR / 4, 256, 0, stream>>>(part, xh, fcw, fcb, pred, nsplit);
}

// Round 18
// 181.267 us; speedup vs baseline: 1.1581x; 1.0908x over previous
//
#include <hip/hip_runtime.h>

#define NR 4000
#define TS 60
#define DF 6
#define HD 64
#define MB 16    // rows per GRU block
#define ARB 32   // rows per attn block

typedef __attribute__((ext_vector_type(8))) short bf8_t;
typedef __attribute__((ext_vector_type(4))) short bf4_t;
typedef __attribute__((ext_vector_type(4))) float f32x4;

__device__ __forceinline__ float sigf(float x) { return 1.0f / (1.0f + __expf(-x)); }
__device__ __forceinline__ float tanhfast(float x) { return 1.0f - 2.0f / (1.0f + __expf(2.0f * x)); }

__device__ __forceinline__ unsigned short f2bf(float v) {
  union { float f; unsigned u; } x; x.f = v;
  unsigned r = (x.u + 0x7fffu + ((x.u >> 16) & 1u)) >> 16;
  return (unsigned short)r;
}
__device__ __forceinline__ float bf2f(unsigned short h) {
  union { unsigned u; float f; } y; y.u = ((unsigned)h) << 16; return y.f;
}
__device__ __forceinline__ void split8(const float* v, bf8_t& hi, bf8_t& lo) {
#pragma unroll
  for (int j = 0; j < 8; ++j) {
    unsigned short h = f2bf(v[j]);
    float rem = v[j] - bf2f(h);
    hi[j] = (short)h;
    lo[j] = (short)f2bf(rem);
  }
}

// ---------------------------------------------------------------------------
// Kernel 1: fused 2-layer GRU via split-bf16 MFMA — round-9 proven (121us).
// Failed alternatives: (256,2) spills (r6); 8-wave dup-rows (r10); msum
// co-residency (r14); setprio (r15); standalone msum (r16); attn LDS-staged
// rel (r17: lost prefetch pipelining, +extra barrier).
// ---------------------------------------------------------------------------
__global__ __launch_bounds__(256, 1) void gru_mfma(
    const float* __restrict__ x,
    const float* __restrict__ Wih0, const float* __restrict__ Whh0,
    const float* __restrict__ bih0, const float* __restrict__ bhh0,
    const float* __restrict__ Wih1, const float* __restrict__ Whh1,
    const float* __restrict__ bih1, const float* __restrict__ bhh1,
    const float* __restrict__ Wac,
    float* __restrict__ xh_out, float* __restrict__ a_out, float* __restrict__ c_out) {
  __shared__ float xldsT[TS][MB][12];
  __shared__ __align__(16) unsigned short h0hiL[2][16][76];
  __shared__ __align__(16) unsigned short h0loL[2][16][76];
  __shared__ __align__(16) unsigned short h1hiL[2][16][76];
  __shared__ __align__(16) unsigned short h1loL[2][16][76];
  __shared__ float red[2][4][MB];

  const int tid = threadIdx.x;
  const int w = tid >> 6;
  const int lane = tid & 63;
  const int lg = lane >> 4;
  const int lm = lane & 15;
  const int unit = w * 16 + lm;
  const int r0 = blockIdx.x * MB;

  for (int idx = tid; idx < MB * 360; idx += 256) {
    int rr = idx / 360, cc = idx - rr * 360;
    int f = cc / 60, t = cc - f * 60;
    xldsT[t][rr][f] = x[(size_t)r0 * 360 + idx];
  }

  bf8_t wB[3][3][2][2];
  {
    const float* mats[3] = {Whh0, Wih1, Whh1};
#pragma unroll
    for (int m = 0; m < 3; ++m)
#pragma unroll
      for (int g = 0; g < 3; ++g)
#pragma unroll
        for (int kt = 0; kt < 2; ++kt) {
          const float* src = mats[m] + (size_t)(g * 64 + unit) * 64 + kt * 32 + 8 * lg;
          float v[8];
          *(float4*)&v[0] = *(const float4*)&src[0];
          *(float4*)&v[4] = *(const float4*)&src[4];
          split8(v, wB[m][g][kt][0], wB[m][g][kt][1]);
        }
  }
  float wih0g[3][DF];
#pragma unroll
  for (int g = 0; g < 3; ++g)
#pragma unroll
    for (int f = 0; f < DF; ++f)
      wih0g[g][f] = Wih0[(size_t)(g * 64 + unit) * DF + f];

  const float bi0r = bih0[unit], bi0z = bih0[64 + unit], bi0n = bih0[128 + unit];
  const float bh0r = bhh0[unit], bh0z = bhh0[64 + unit], bh0n = bhh0[128 + unit];
  const float c1R = bih1[unit] + bhh1[unit];
  const float c1Z = bih1[64 + unit] + bhh1[64 + unit];
  const float b1xn = bih1[128 + unit], b1hn = bhh1[128 + unit];

  bf8_t a0[2][2], a1[2][2];
  bf8_t zf = {};
#pragma unroll
  for (int kt = 0; kt < 2; ++kt)
#pragma unroll
    for (int h = 0; h < 2; ++h) { a0[kt][h] = zf; a1[kt][h] = zf; }
  float h0c[4] = {0.f, 0.f, 0.f, 0.f};
  float h1c[4] = {0.f, 0.f, 0.f, 0.f};

  __syncthreads();

#define MF(acc, A, B) acc = __builtin_amdgcn_mfma_f32_16x16x32_bf16(A, B, acc, 0, 0, 0)
#define MF3(acc, Af, Bf) do { \
    MF(acc, Af[0], Bf[0]); MF(acc, Af[0], Bf[1]); MF(acc, Af[1], Bf[0]); } while (0)

  for (int p = 0; p <= TS; ++p) {
    const bool doL0 = (p < TS);
    const bool doL1 = (p >= 1);
    const int par = p & 1;
    f32x4 aR, aZ, aN;
    float xn0[4];
    if (doL0) {
#pragma unroll
      for (int i = 0; i < 4; ++i) {
        const int row = 4 * lg + i;
        const float* xb = &xldsT[p][row][0];
        float4 x4 = *(const float4*)xb;
        float2 x2 = *(const float2*)(xb + 4);
        float sr = bi0r, sz = bi0z, sn = bi0n;
        sr = fmaf(wih0g[0][0], x4.x, sr); sz = fmaf(wih0g[1][0], x4.x, sz); sn = fmaf(wih0g[2][0], x4.x, sn);
        sr = fmaf(wih0g[0][1], x4.y, sr); sz = fmaf(wih0g[1][1], x4.y, sz); sn = fmaf(wih0g[2][1], x4.y, sn);
        sr = fmaf(wih0g[0][2], x4.z, sr); sz = fmaf(wih0g[1][2], x4.z, sz); sn = fmaf(wih0g[2][2], x4.z, sn);
        sr = fmaf(wih0g[0][3], x4.w, sr); sz = fmaf(wih0g[1][3], x4.w, sz); sn = fmaf(wih0g[2][3], x4.w, sn);
        sr = fmaf(wih0g[0][4], x2.x, sr); sz = fmaf(wih0g[1][4], x2.x, sz); sn = fmaf(wih0g[2][4], x2.x, sn);
        sr = fmaf(wih0g[0][5], x2.y, sr); sz = fmaf(wih0g[1][5], x2.y, sz); sn = fmaf(wih0g[2][5], x2.y, sn);
        aR[i] = sr + bh0r;
        aZ[i] = sz + bh0z;
        aN[i] = bh0n;
        xn0[i] = sn;
      }
#pragma unroll
      for (int kt = 0; kt < 2; ++kt) {
        MF3(aR, a0[kt], wB[0][0][kt]);
        MF3(aZ, a0[kt], wB[0][1][kt]);
        MF3(aN, a0[kt], wB[0][2][kt]);
      }
    }
    f32x4 R1, Z1, XN, HN;
    if (doL1) {
#pragma unroll
      for (int i = 0; i < 4; ++i) { R1[i] = c1R; Z1[i] = c1Z; XN[i] = b1xn; HN[i] = b1hn; }
#pragma unroll
      for (int kt = 0; kt < 2; ++kt) {
        MF3(R1, a0[kt], wB[1][0][kt]);
        MF3(Z1, a0[kt], wB[1][1][kt]);
        MF3(XN, a0[kt], wB[1][2][kt]);
        MF3(R1, a1[kt], wB[2][0][kt]);
        MF3(Z1, a1[kt], wB[2][1][kt]);
        MF3(HN, a1[kt], wB[2][2][kt]);
      }
    }
    if (doL0) {
#pragma unroll
      for (int i = 0; i < 4; ++i) {
        float r = sigf(aR[i]);
        float z = sigf(aZ[i]);
        float n = tanhfast(xn0[i] + r * aN[i]);
        h0c[i] = n + z * (h0c[i] - n);
        const int row = 4 * lg + i;
        unsigned u = __float_as_uint(h0c[i]);
        h0hiL[par][row][unit] = (unsigned short)(u >> 16);
        float lo = h0c[i] - __uint_as_float(u & 0xffff0000u);
        h0loL[par][row][unit] = (unsigned short)(__float_as_uint(lo) >> 16);
      }
    }
    if (doL1) {
#pragma unroll
      for (int i = 0; i < 4; ++i) {
        float r = sigf(R1[i]);
        float z = sigf(Z1[i]);
        float n = tanhfast(XN[i] + r * HN[i]);
        h1c[i] = n + z * (h1c[i] - n);
      }
      if (p < TS) {
#pragma unroll
        for (int i = 0; i < 4; ++i) {
          const int row = 4 * lg + i;
          unsigned u = __float_as_uint(h1c[i]);
          h1hiL[par][row][unit] = (unsigned short)(u >> 16);
          float lo = h1c[i] - __uint_as_float(u & 0xffff0000u);
          h1loL[par][row][unit] = (unsigned short)(__float_as_uint(lo) >> 16);
        }
      }
    }
    __syncthreads();
    if (p < TS) {
#pragma unroll
      for (int kt = 0; kt < 2; ++kt) {
        const int cb = kt * 32 + 8 * lg;
        bf4_t u0 = *(const bf4_t*)&h0hiL[par][lm][cb];
        bf4_t u1 = *(const bf4_t*)&h0hiL[par][lm][cb + 4];
        a0[kt][0] = __builtin_shufflevector(u0, u1, 0, 1, 2, 3, 4, 5, 6, 7);
        bf4_t l0 = *(const bf4_t*)&h0loL[par][lm][cb];
        bf4_t l1 = *(const bf4_t*)&h0loL[par][lm][cb + 4];
        a0[kt][1] = __builtin_shufflevector(l0, l1, 0, 1, 2, 3, 4, 5, 6, 7);
      }
      if (p >= 1) {
#pragma unroll
        for (int kt = 0; kt < 2; ++kt) {
          const int cb = kt * 32 + 8 * lg;
          bf4_t u0 = *(const bf4_t*)&h1hiL[par][lm][cb];
          bf4_t u1 = *(const bf4_t*)&h1hiL[par][lm][cb + 4];
          a1[kt][0] = __builtin_shufflevector(u0, u1, 0, 1, 2, 3, 4, 5, 6, 7);
          bf4_t l0 = *(const bf4_t*)&h1loL[par][lm][cb];
          bf4_t l1 = *(const bf4_t*)&h1loL[par][lm][cb + 4];
          a1[kt][1] = __builtin_shufflevector(l0, l1, 0, 1, 2, 3, 4, 5, 6, 7);
        }
      }
    }
  }
#undef MF3
#undef MF

#pragma unroll
  for (int i = 0; i < 4; ++i)
    xh_out[(size_t)(r0 + 4 * lg + i) * HD + unit] = h1c[i];

  const float WaU = Wac[unit], WcU = Wac[64 + unit];
#pragma unroll
  for (int i = 0; i < 4; ++i) {
    float av = h1c[i] * WaU, cv = h1c[i] * WcU;
#pragma unroll
    for (int off = 1; off < 16; off <<= 1) {
      av += __shfl_xor(av, off, 64);
      cv += __shfl_xor(cv, off, 64);
    }
    if (lm == 0) {
      red[0][w][4 * lg + i] = av;
      red[1][w][4 * lg + i] = cv;
    }
  }
  __syncthreads();
  if (tid < MB) {
    a_out[r0 + tid] = red[0][0][tid] + red[0][1][tid] + red[0][2][tid] + red[0][3][tid];
    c_out[r0 + tid] = red[1][0][tid] + red[1][1][tid] + red[1][2][tid] + red[1][3][tid];
  }
}

// ---------------------------------------------------------------------------
// Kernel 2a: attention PARTIAL, 32 rows/block x 4 rows/thread, rel-direct
// with one-chunk register prefetch (round-9 proven, ~43us). Only change vs
// round 9: rel prefetch as 3x float2 (addresses are 24B-multiples -> 8B
// aligned; halves load-instruction count on this latency-bound path).
// ---------------------------------------------------------------------------
__global__ __launch_bounds__(256) void attn_part(
    const float* __restrict__ rel,
    const float* __restrict__ xh,
    const float* __restrict__ aArr, const float* __restrict__ cArr,
    const float* __restrict__ bSc,
    float* __restrict__ part, int jsl, int lsp) {
  __shared__ float xhl[64][68];
  __shared__ float pbuf[ARB][64];
  __shared__ float cls[1024];

  const int tid = threadIdx.x;
  const int rg = tid >> 5;
  const int tk = tid & 31;
  const int bx = blockIdx.x;
  const int ib = bx >> lsp;
  const int js = bx & ((1 << lsp) - 1);
  const int jbeg = js * jsl;
  const int jend = (jbeg + jsl < NR) ? (jbeg + jsl) : NR;
  const int nch = (jend - jbeg + 63) >> 6;
  const float bb = bSc[0];

  int irow[4];
  float aib[4];
#pragma unroll
  for (int rr = 0; rr < 4; ++rr) {
    irow[rr] = ib * ARB + rg + 8 * rr;
    aib[rr] = aArr[irow[rr]] + bb;
  }

  for (int t = tid; t < jsl; t += 256)
    cls[t] = (jbeg + t < NR) ? cArr[jbeg + t] : 0.f;

  float2 pr[4][3];
#pragma unroll
  for (int rr = 0; rr < 4; ++rr) {
    const float2* rp = (const float2*)(rel + (size_t)irow[rr] * (3 * NR) +
                                       (size_t)(jbeg + 2 * tk) * 3);
#pragma unroll
    for (int e = 0; e < 3; ++e) pr[rr][e] = rp[e];
  }

  float m[4], s[4], acc0[4], acc1[4];
#pragma unroll
  for (int rr = 0; rr < 4; ++rr) { m[rr] = -3.0e38f; s[rr] = 0.f; acc0[rr] = 0.f; acc1[rr] = 0.f; }

  for (int c = 0; c < nch; ++c) {
    const int j0 = jbeg + c * 64;
    __syncthreads();
    {
      const int jj = tid >> 2, seg = tid & 3;
      const int j = j0 + jj;
      if (j < NR) {
        const float4* src = (const float4*)(xh + (size_t)j * 64 + seg * 16);
#pragma unroll
        for (int q = 0; q < 4; ++q) *(float4*)&xhl[jj][seg * 16 + 4 * q] = src[q];
      } else {
        float4 z = {0.f, 0.f, 0.f, 0.f};
#pragma unroll
        for (int q = 0; q < 4; ++q) *(float4*)&xhl[jj][seg * 16 + 4 * q] = z;
      }
    }

    const int jb = j0 + 2 * tk;
    const bool ok = (jb < jend);
    const int ci = c * 64 + 2 * tk;
    const float cl0 = cls[ci], cl1 = cls[ci + 1];

#pragma unroll
    for (int rr = 0; rr < 4; ++rr) {
      float msum0 = pr[rr][0].x + pr[rr][0].y + pr[rr][1].x;
      float msum1 = pr[rr][1].y + pr[rr][2].x + pr[rr][2].y;
      float w0 = aib[rr] + cl0, w1 = aib[rr] + cl1;
      w0 = (w0 > 0.f) ? w0 : 0.01f * w0;
      w1 = (w1 > 0.f) ? w1 : 0.01f * w1;
      float v0 = (!ok) ? -3.0e37f : ((msum0 == 0.f) ? -1.0e6f : msum0 * w0);
      float v1 = (!ok) ? -3.0e37f : ((msum1 == 0.f) ? -1.0e6f : msum1 * w1);

      float lm2 = fmaxf(v0, v1);
#pragma unroll
      for (int off = 16; off; off >>= 1) lm2 = fmaxf(lm2, __shfl_xor(lm2, off, 32));
      const float mn = fmaxf(m[rr], lm2);
      const float f = __expf(m[rr] - mn);
      const float p0 = __expf(v0 - mn);
      const float p1 = __expf(v1 - mn);
      float ls = p0 + p1;
#pragma unroll
      for (int off = 16; off; off >>= 1) ls += __shfl_xor(ls, off, 32);
      s[rr] = s[rr] * f + ls;
      acc0[rr] *= f;
      acc1[rr] *= f;
      m[rr] = mn;
      pbuf[rg + 8 * rr][2 * tk] = p0;
      pbuf[rg + 8 * rr][2 * tk + 1] = p1;  // same half-wave writes & reads
    }

    if (c + 1 < nch) {
      const int jn = j0 + 64 + 2 * tk;
      if (jn < jend) {
#pragma unroll
        for (int rr = 0; rr < 4; ++rr) {
          const float2* rp = (const float2*)(rel + (size_t)irow[rr] * (3 * NR) +
                                             (size_t)jn * 3);
#pragma unroll
          for (int e = 0; e < 3; ++e) pr[rr][e] = rp[e];
        }
      }
    }

    __syncthreads();

#pragma unroll 2
    for (int j4 = 0; j4 < 16; ++j4) {
      float4 pv0 = *(const float4*)&pbuf[rg][4 * j4];
      float4 pv1 = *(const float4*)&pbuf[rg + 8][4 * j4];
      float4 pv2 = *(const float4*)&pbuf[rg + 16][4 * j4];
      float4 pv3 = *(const float4*)&pbuf[rg + 24][4 * j4];
      float2 x0 = *(const float2*)&xhl[4 * j4 + 0][2 * tk];
      float2 x1 = *(const float2*)&xhl[4 * j4 + 1][2 * tk];
      float2 x2 = *(const float2*)&xhl[4 * j4 + 2][2 * tk];
      float2 x3 = *(const float2*)&xhl[4 * j4 + 3][2 * tk];
      acc0[0] = fmaf(pv0.x, x0.x, acc0[0]); acc1[0] = fmaf(pv0.x, x0.y, acc1[0]);
      acc0[0] = fmaf(pv0.y, x1.x, acc0[0]); acc1[0] = fmaf(pv0.y, x1.y, acc1[0]);
      acc0[0] = fmaf(pv0.z, x2.x, acc0[0]); acc1[0] = fmaf(pv0.z, x2.y, acc1[0]);
      acc0[0] = fmaf(pv0.w, x3.x, acc0[0]); acc1[0] = fmaf(pv0.w, x3.y, acc1[0]);
      acc0[1] = fmaf(pv1.x, x0.x, acc0[1]); acc1[1] = fmaf(pv1.x, x0.y, acc1[1]);
      acc0[1] = fmaf(pv1.y, x1.x, acc0[1]); acc1[1] = fmaf(pv1.y, x1.y, acc1[1]);
      acc0[1] = fmaf(pv1.z, x2.x, acc0[1]); acc1[1] = fmaf(pv1.z, x2.y, acc1[1]);
      acc0[1] = fmaf(pv1.w, x3.x, acc0[1]); acc1[1] = fmaf(pv1.w, x3.y, acc1[1]);
      acc0[2] = fmaf(pv2.x, x0.x, acc0[2]); acc1[2] = fmaf(pv2.x, x0.y, acc1[2]);
      acc0[2] = fmaf(pv2.y, x1.x, acc0[2]); acc1[2] = fmaf(pv2.y, x1.y, acc1[2]);
      acc0[2] = fmaf(pv2.z, x2.x, acc0[2]); acc1[2] = fmaf(pv2.z, x2.y, acc1[2]);
      acc0[2] = fmaf(pv2.w, x3.x, acc0[2]); acc1[2] = fmaf(pv2.w, x3.y, acc1[2]);
      acc0[3] = fmaf(pv3.x, x0.x, acc0[3]); acc1[3] = fmaf(pv3.x, x0.y, acc1[3]);
      acc0[3] = fmaf(pv3.y, x1.x, acc0[3]); acc1[3] = fmaf(pv3.y, x1.y, acc1[3]);
      acc0[3] = fmaf(pv3.z, x2.x, acc0[3]); acc1[3] = fmaf(pv3.z, x2.y, acc1[3]);
      acc0[3] = fmaf(pv3.w, x3.x, acc0[3]); acc1[3] = fmaf(pv3.w, x3.y, acc1[3]);
    }
  }

#pragma unroll
  for (int rr = 0; rr < 4; ++rr) {
    float* base = part + ((size_t)bx * ARB + rg + 8 * rr) * 66;
    if (tk == 0) { base[0] = m[rr]; base[1] = s[rr]; }
    base[2 + 2 * tk] = acc0[rr];
    base[3 + 2 * tk] = acc1[rr];
  }
}

// ---------------------------------------------------------------------------
// Kernel 2b: combine partials + final FC. NR/4 blocks x 256 (4 rows/block).
// ---------------------------------------------------------------------------
__global__ __launch_bounds__(256) void attn_combine(
    const float* __restrict__ part,
    const float* __restrict__ xh,
    const float* __restrict__ fcw, const float* __restrict__ fcb,
    float* __restrict__ pred, int nsplit) {
  const int tid = threadIdx.x;
  const int r = blockIdx.x * 4 + (tid >> 6);
  const int lane = tid & 63;
  const int ib = r / ARB, il = r % ARB;

  float mstar = -3.0e38f;
  for (int k = 0; k < nsplit; ++k) {
    const float* b = part + ((size_t)(ib * nsplit + k) * ARB + il) * 66;
    mstar = fmaxf(mstar, b[0]);
  }
  float sstar = 0.f, onum = 0.f;
  for (int k = 0; k < nsplit; ++k) {
    const float* b = part + ((size_t)(ib * nsplit + k) * ARB + il) * 66;
    const float wk = __expf(b[0] - mstar);
    sstar = fmaf(wk, b[1], sstar);
    onum = fmaf(wk, b[2 + lane], onum);
  }
  const float o = onum / sstar;
  float p = fcw[lane] * xh[(size_t)r * HD + lane] + fcw[64 + lane] * o;
#pragma unroll
  for (int off = 32; off; off >>= 1) p += __shfl_xor(p, off, 64);
  if (lane == 0) pred[r] = p + fcb[0];
}

extern "C" void kernel_launch(void* const* d_in, const int* in_sizes, int n_in,
                              void* d_out, int out_size, void* d_ws, size_t ws_size,
                              hipStream_t stream) {
  const float* x    = (const float*)d_in[0];
  const float* rel  = (const float*)d_in[1];
  const float* Wih0 = (const float*)d_in[2];
  const float* Whh0 = (const float*)d_in[3];
  const float* bih0 = (const float*)d_in[4];
  const float* bhh0 = (const float*)d_in[5];
  const float* Wih1 = (const float*)d_in[6];
  const float* Whh1 = (const float*)d_in[7];
  const float* bih1 = (const float*)d_in[8];
  const float* bhh1 = (const float*)d_in[9];
  const float* Wac  = (const float*)d_in[10];
  const float* bSc  = (const float*)d_in[11];
  const float* fcw  = (const float*)d_in[12];
  const float* fcb  = (const float*)d_in[13];

  float* xh = (float*)d_ws;
  float* aA = xh + (size_t)NR * HD;
  float* cA = aA + NR;
  float* part = cA + NR;
  float* pred = (float*)d_out;

  const size_t headF = (size_t)NR * HD + 2 * NR;  // floats
  auto needB = [&](int ns) {
    return (headF + (size_t)(NR / ARB) * ns * ARB * 66) * 4;
  };
  int nsplit = 8, lsp = 3;
  if (needB(8) > ws_size) { nsplit = 4; lsp = 2; }
  const int jsl = NR / nsplit;

  gru_mfma<<<NR / MB, 256, 0, stream>>>(x, Wih0, Whh0, bih0, bhh0, Wih1, Whh1,
                                        bih1, bhh1, Wac, xh, aA, cA);
  attn_part<<<(NR / ARB) * nsplit, 256, 0, stream>>>(rel, xh, aA, cA, bSc,
                                                     part, jsl, lsp);
  attn_combine<<<NR / 4, 256, 0, stream>>>(part, xh, fcw, fcb, pred, nsplit);
}